// Round 7
// baseline (316.050 us; speedup 1.0000x reference)
//
#include <hip/hip_runtime.h>
#include <math.h>

// out[n,o] = exp(A)*cos(B)
//   A = sum_i ln(R)*Wr - K*Wi ;  B = sum_i ln(R)*Wi + K*Wr
//   R = 1 + g*(|x|-1),  K = pi*(x<0)*g,  g = clip(G,0,1)
// n=8192, i=o=128.
//
// R17: ABLATION ROUND. Four structurally different mains (R11/R14/R15b/R16)
// all land at ~40-43us while their supposed bottlenecks differ -> stop
// guessing, measure the terms. One templated kernel, 4 timed dispatches:
//   V1 REP=4: loop without LDS row reads (regs preloaded)  -> LDS term
//   V2 REP=4: loop without weight VMEM stream (preloaded)  -> weight term
//   V3 REP=4: loop without __log2f (l2 = t2)               -> TRANS term
//   V0 REP=1: unmodified R16 main, runs LAST -> correct output.
// REP=4 (rep-rotated index, no hoisting) inflates each ablated loop ~4x so
// every variant clears the 41us fill floor and appears in top-5 (_ord maps
// dispatch->variant). Full-equivalent ~= 4x37+3 ~= 150us.
// Decision: V1<<150 -> LDS-broadcast wall; V2<<150 -> weight-stream wall;
// V3<<150 -> TRANS-share; all ~=150 -> structural issue/latency (occupancy).
// Total this round ~400us BY DESIGN (diagnostic).
// Geometry (all variants): 512 blocks x 512 thr (8 waves; h=o-half,
// iq=i-quarter), RPB=16, LB(512,4), 32KB LDS.

#define NROWS 8192
#define DIM   128
#define RPB   16
#define NT    512
#define PI_F  3.14159265358979323846f
#define LN2_F 0.69314718055994530942f

typedef float v2f __attribute__((ext_vector_type(2)));

static __device__ __forceinline__ v2f vfma2(v2f a, v2f b, v2f c) {
    return __builtin_elementwise_fma(a, b, c);
}

// prep: 64 blocks x 256. wq[i*128+o] = (ln2*wr, ln2*wi, g, unused)
//                        wb[i*128+o] = (-pi*g*wi, pi*g*wr)
__global__ __launch_bounds__(256) void prep(
    const float* __restrict__ Wr, const float* __restrict__ Wi,
    const float* __restrict__ G,
    float4* __restrict__ wq, float2* __restrict__ wb)
{
    int t = blockIdx.x * 256 + threadIdx.x;
    if (t < DIM * DIM) {
        float g  = fminf(fmaxf(G[t], 0.0f), 1.0f);
        float wr = Wr[t], wi = Wi[t];
        wq[t] = make_float4(LN2_F * wr, LN2_F * wi, g, 0.0f);
        wb[t] = make_float2(-PI_F * g * wi, PI_F * g * wr);
    }
}

// V: 0=full  1=no-LDS-in-loop  2=no-weight-VMEM-in-loop  3=no-log
template <int V, int REP>
__global__ __launch_bounds__(NT, 4) void main_kernel(
    const float* __restrict__ x, const float4* __restrict__ wq,
    const float2* __restrict__ wb, float* __restrict__ out)
{
    __shared__ float sbuf[4 * RPB * DIM];
    float* am1p = sbuf;               // [DIM][RPB]
    float* sfp  = sbuf + DIM * RPB;   // [DIM][RPB]

    const int tid   = threadIdx.x;
    const int lane  = tid & 63;
    const int w     = tid >> 6;
    const int h     = w & 1;
    const int iq    = w >> 1;
    const int i0    = iq * 32;
    const int o     = h * 64 + lane;
    const int nbase = blockIdx.x * RPB;

    // Stage x tile (16 rows x 128 i): float4 coalesced.
    {
        const float4* xb = (const float4*)(x + (size_t)nbase * DIM);
        float4 v = xb[tid];
        int e = tid * 4;
        int i = e & (DIM - 1), r = e >> 7;
        float vv[4] = {v.x, v.y, v.z, v.w};
#pragma unroll
        for (int k = 0; k < 4; ++k) {
            am1p[(i + k) * RPB + r] = fabsf(vv[k]) - 1.0f;
            sfp[(i + k) * RPB + r]  = (vv[k] < 0.0f) ? 1.0f : 0.0f;
        }
    }
    __syncthreads();

    v2f accA[8], accB[8];
#pragma unroll
    for (int p = 0; p < 8; ++p) { accA[p] = (v2f){0.f, 0.f}; accB[p] = (v2f){0.f, 0.f}; }

    const float4* wqp = wq + (size_t)i0 * DIM + o;
    const float2* wbp = wb + (size_t)i0 * DIM + o;

    // Weight pipeline regs (V2: loaded once, never rotated).
    float4 wq0 = wqp[0], wq1 = (V == 2) ? wq0 : wqp[DIM];
    float2 wb0 = wbp[0], wb1 = (V == 2) ? wb0 : wbp[DIM];

    // V1: row operands preloaded ONCE (LDS reads removed from the loop).
    float4 pA, pB, pC, pD, tA, tB, tC, tD;
    if (V == 1) {
        const float4* a4 = (const float4*)(am1p + i0 * RPB);
        const float4* s4 = (const float4*)(sfp  + i0 * RPB);
        pA = a4[0]; pB = a4[1]; pC = a4[2]; pD = a4[3];
        tA = s4[0]; tB = s4[1]; tC = s4[2]; tD = s4[3];
    }

#pragma unroll 1
    for (int rep = 0; rep < REP; ++rep) {
#pragma unroll 2
        for (int ii = 0; ii < 32; ++ii) {
            const int iw = (ii + rep) & 31;      // rep-rotated, same range
            const int p2 = (iw + 2) & 31;

            float4 wqn; float2 wbn;
            if (V != 2) { wqn = wqp[(size_t)p2 * DIM]; wbn = wbp[(size_t)p2 * DIM]; }

            const int i = i0 + iw;
            float4 aA, aB, aC, aD, sA, sB, sC, sD;
            if (V == 1) {
                aA = pA; aB = pB; aC = pC; aD = pD;
                sA = tA; sB = tB; sC = tC; sD = tD;
            } else {
                const float4* a4 = (const float4*)(am1p + i * RPB);
                const float4* s4 = (const float4*)(sfp  + i * RPB);
                aA = a4[0]; aB = a4[1]; aC = a4[2]; aD = a4[3];
                sA = s4[0]; sB = s4[1]; sC = s4[2]; sD = s4[3];
            }

            const float g    = wq0.z;
            const float wrl  = wq0.x, wil = wq0.y;
            const float ngwi = wb0.x, pgwr = wb0.y;
            const v2f gg2   = {g, g};
            const v2f wrl2  = {wrl, wrl};
            const v2f wil2  = {wil, wil};
            const v2f ngwi2 = {ngwi, ngwi};
            const v2f pgwr2 = {pgwr, pgwr};
            const v2f one2  = {1.0f, 1.0f};

#define ROWPAIR(mx, my, sx, sy, idx)                                        \
            do {                                                            \
                v2f t2 = vfma2((v2f){mx, my}, gg2, one2);                   \
                v2f l2;                                                     \
                if (V == 3) { l2 = t2; }                                    \
                else { l2 = (v2f){ __log2f(t2.x), __log2f(t2.y) }; }        \
                v2f s2 = {sx, sy};                                          \
                accA[idx] = vfma2(l2, wrl2, vfma2(s2, ngwi2, accA[idx]));   \
                accB[idx] = vfma2(l2, wil2, vfma2(s2, pgwr2, accB[idx]));   \
            } while (0)

            ROWPAIR(aA.x, aA.y, sA.x, sA.y, 0);
            ROWPAIR(aA.z, aA.w, sA.z, sA.w, 1);
            ROWPAIR(aB.x, aB.y, sB.x, sB.y, 2);
            ROWPAIR(aB.z, aB.w, sB.z, sB.w, 3);
            ROWPAIR(aC.x, aC.y, sC.x, sC.y, 4);
            ROWPAIR(aC.z, aC.w, sC.z, sC.w, 5);
            ROWPAIR(aD.x, aD.y, sD.x, sD.y, 6);
            ROWPAIR(aD.z, aD.w, sD.z, sD.w, 7);
#undef ROWPAIR

            if (V != 2) { wq0 = wq1; wq1 = wqn; wb0 = wb1; wb1 = wbn; }
        }
    }

    // Epilogue: iq-reduce via the full 32 KB buffer, A then B.
    float* pP = sbuf;                        // [4][RPB][DIM]
    const int c4 = tid * 4;

    __syncthreads();
#pragma unroll
    for (int p = 0; p < 8; ++p) {
        pP[iq * (RPB * DIM) + (2 * p) * DIM + o]     = accA[p].x;
        pP[iq * (RPB * DIM) + (2 * p + 1) * DIM + o] = accA[p].y;
    }
    __syncthreads();
    float4 A4 = make_float4(0.f, 0.f, 0.f, 0.f);
#pragma unroll
    for (int q2 = 0; q2 < 4; ++q2) {
        float4 t = *(const float4*)&pP[q2 * (RPB * DIM) + c4];
        A4.x += t.x; A4.y += t.y; A4.z += t.z; A4.w += t.w;
    }
    __syncthreads();
#pragma unroll
    for (int p = 0; p < 8; ++p) {
        pP[iq * (RPB * DIM) + (2 * p) * DIM + o]     = accB[p].x;
        pP[iq * (RPB * DIM) + (2 * p + 1) * DIM + o] = accB[p].y;
    }
    __syncthreads();
    float4 B4 = make_float4(0.f, 0.f, 0.f, 0.f);
#pragma unroll
    for (int q2 = 0; q2 < 4; ++q2) {
        float4 t = *(const float4*)&pP[q2 * (RPB * DIM) + c4];
        B4.x += t.x; B4.y += t.y; B4.z += t.z; B4.w += t.w;
    }

    float4 res;
    res.x = __expf(A4.x) * __cosf(B4.x);
    res.y = __expf(A4.y) * __cosf(B4.y);
    res.z = __expf(A4.z) * __cosf(B4.z);
    res.w = __expf(A4.w) * __cosf(B4.w);
    ((float4*)(out + (size_t)nbase * DIM))[tid] = res;
}

// Fallback (no workspace): R14's verified LDS-plane kernel (RPB=8 geometry).
__global__ __launch_bounds__(NT, 4) void fb_kernel(
    const float* __restrict__ x,
    const float* __restrict__ Wr, const float* __restrict__ Wi,
    const float* __restrict__ G, float* __restrict__ out)
{
    __shared__ float sbuf[4 * 8 * DIM];
    float* am1p = sbuf;
    float* psp  = sbuf + DIM * 8;

    const int tid   = threadIdx.x;
    const int o     = tid & (DIM - 1);
    const int q     = tid >> 7;
    const int nbase = blockIdx.x * 8;

    {
        const float* xb = x + (size_t)nbase * DIM;
        float2 v = ((const float2*)xb)[tid];
        int e = tid * 2;
        int i = e & (DIM - 1), r = e >> 7;
        am1p[i * 8 + r]       = fabsf(v.x) - 1.0f;
        am1p[(i + 1) * 8 + r] = fabsf(v.y) - 1.0f;
        psp[i * 8 + r]        = (v.x < 0.0f) ? PI_F : 0.0f;
        psp[(i + 1) * 8 + r]  = (v.y < 0.0f) ? PI_F : 0.0f;
    }
    __syncthreads();

    v2f accA[4], accB[4];
#pragma unroll
    for (int p = 0; p < 4; ++p) { accA[p] = (v2f){0.f, 0.f}; accB[p] = (v2f){0.f, 0.f}; }

    const int ibase = q * 32;
#pragma unroll 4
    for (int ii = 0; ii < 32; ++ii) {
        const int i = ibase + ii;
        const int wi_idx = i * DIM + o;
        float g   = fminf(fmaxf(G[wi_idx], 0.0f), 1.0f);
        float wrl = LN2_F * Wr[wi_idx];
        float wil = LN2_F * Wi[wi_idx];
        const float ngwi = -g * (wil * (1.0f / LN2_F));
        const float gwr  =  g * (wrl * (1.0f / LN2_F));
        const v2f gg2 = {g, g}, wrl2 = {wrl, wrl}, wil2 = {wil, wil};
        const v2f ngwi2 = {ngwi, ngwi}, gwr2 = {gwr, gwr}, one2 = {1.f, 1.f};

        const float4* a4 = (const float4*)(am1p + i * 8);
        const float4* p4 = (const float4*)(psp  + i * 8);
        float4 a03 = a4[0], a47 = a4[1];
        float4 s03 = p4[0], s47 = p4[1];

#define ROWPAIR(mx, my, sx, sy, idx)                                        \
        do {                                                                \
            v2f t2 = vfma2((v2f){mx, my}, gg2, one2);                       \
            v2f l2 = { __log2f(t2.x), __log2f(t2.y) };                      \
            v2f s2 = {sx, sy};                                              \
            accA[idx] = vfma2(l2, wrl2, vfma2(s2, ngwi2, accA[idx]));       \
            accB[idx] = vfma2(l2, wil2, vfma2(s2, gwr2,  accB[idx]));       \
        } while (0)

        ROWPAIR(a03.x, a03.y, s03.x, s03.y, 0);
        ROWPAIR(a03.z, a03.w, s03.z, s03.w, 1);
        ROWPAIR(a47.x, a47.y, s47.x, s47.y, 2);
        ROWPAIR(a47.z, a47.w, s47.z, s47.w, 3);
#undef ROWPAIR
    }

    float* pP = sbuf;
    const int c = tid * 2;
    const int r = c >> 7, oo = c & (DIM - 1);

    __syncthreads();
#pragma unroll
    for (int p = 0; p < 4; ++p) {
        pP[q * (8 * DIM) + (2 * p) * DIM + o]     = accA[p].x;
        pP[q * (8 * DIM) + (2 * p + 1) * DIM + o] = accA[p].y;
    }
    __syncthreads();
    v2f A = {0.f, 0.f};
#pragma unroll
    for (int qq = 0; qq < 4; ++qq)
        A += *(const v2f*)&pP[qq * (8 * DIM) + r * DIM + oo];
    __syncthreads();
#pragma unroll
    for (int p = 0; p < 4; ++p) {
        pP[q * (8 * DIM) + (2 * p) * DIM + o]     = accB[p].x;
        pP[q * (8 * DIM) + (2 * p + 1) * DIM + o] = accB[p].y;
    }
    __syncthreads();
    v2f B = {0.f, 0.f};
#pragma unroll
    for (int qq = 0; qq < 4; ++qq)
        B += *(const v2f*)&pP[qq * (8 * DIM) + r * DIM + oo];

    float2 res;
    res.x = __expf(A.x) * __cosf(B.x);
    res.y = __expf(A.y) * __cosf(B.y);
    *(float2*)&out[(size_t)(nbase + r) * DIM + oo] = res;
}

extern "C" void kernel_launch(void* const* d_in, const int* in_sizes, int n_in,
                              void* d_out, int out_size, void* d_ws, size_t ws_size,
                              hipStream_t stream) {
    const float* x  = (const float*)d_in[0];
    const float* Wr = (const float*)d_in[1];
    const float* Wi = (const float*)d_in[2];
    const float* G  = (const float*)d_in[3];
    float* out = (float*)d_out;

    const size_t wq_bytes = (size_t)DIM * DIM * sizeof(float4);   // 256 KB
    const size_t wb_bytes = (size_t)DIM * DIM * sizeof(float2);   // 128 KB
    if (ws_size >= wq_bytes + wb_bytes) {
        float4* wq = (float4*)d_ws;
        float2* wb = (float2*)((char*)d_ws + wq_bytes);
        prep<<<(DIM * DIM + 255) / 256, 256, 0, stream>>>(Wr, Wi, G, wq, wb);
        // Ablation dispatches (garbage output, overwritten by final V0):
        main_kernel<1, 4><<<NROWS / RPB, NT, 0, stream>>>(x, wq, wb, out); // no-LDS
        main_kernel<2, 4><<<NROWS / RPB, NT, 0, stream>>>(x, wq, wb, out); // no-wVMEM
        main_kernel<3, 4><<<NROWS / RPB, NT, 0, stream>>>(x, wq, wb, out); // no-log
        // Real kernel, last:
        main_kernel<0, 1><<<NROWS / RPB, NT, 0, stream>>>(x, wq, wb, out);
    } else {
        fb_kernel<<<NROWS / 8, NT, 0, stream>>>(x, Wr, Wi, G, out);
    }
}

// Round 8
// 88.612 us; speedup vs baseline: 3.5667x; 3.5667x over previous
//
#include <hip/hip_runtime.h>
#include <math.h>

// out[n,o] = exp(A)*cos(B)
//   A = sum_i ln(R)*Wr - K*Wi ;  B = sum_i ln(R)*Wi + K*Wr
//   R = 1 + g*(|x|-1),  K = pi*(x<0)*g,  g = clip(G,0,1)
// n=8192, i=o=128.
//
// R18 = R16 DE-PACKED: scalar v_fma_f32 instead of v_pk_fma_f32.
// R17 ablation: V1(no-LDS)=V2(no-weights)=V3(no-log)=96.0us, VALUBusy
// 70-75% -> the loop is exec-bound on the one stream all variants share:
// the packed-FMA chain. Unique consistent model: v_pk_fma_f32 runs at
// 8cy/wave64 (HALF the FLOP rate of 2x scalar v_fma_f32 at 2cy each).
// Fits everything: REP4 = 40pk*8cy*32*4*4w ~ 68us+C ~= 96 (meas);
// REP1 ~ 17+22 ~= 40 (meas); all four prior structures tied at ~40-43
// because ALL used v2f packing. Fix: scalar fma per row (5 fma + 1 log),
// asm("" : "+v"(l)) per row blocks SLP re-packing. Identical math order
// per cell -> same absmax. Geometry/staging/epilogue byte-equal to R16.
// Predict: loop 17->9-10us, main ~30 (below fills), total 88.3 -> 76-79.
// If unchanged: pk hypothesis dead, R19 attacks the ~22us overhead C.

#define NROWS 8192
#define DIM   128
#define RPB   16
#define NT    512
#define PI_F  3.14159265358979323846f
#define LN2_F 0.69314718055994530942f

typedef float v2f __attribute__((ext_vector_type(2)));

static __device__ __forceinline__ v2f vfma2(v2f a, v2f b, v2f c) {
    return __builtin_elementwise_fma(a, b, c);
}

// prep: 64 blocks x 256. wq[i*128+o] = (ln2*wr, ln2*wi, g, unused)
//                        wb[i*128+o] = (-pi*g*wi, pi*g*wr)
__global__ __launch_bounds__(256) void prep(
    const float* __restrict__ Wr, const float* __restrict__ Wi,
    const float* __restrict__ G,
    float4* __restrict__ wq, float2* __restrict__ wb)
{
    int t = blockIdx.x * 256 + threadIdx.x;
    if (t < DIM * DIM) {
        float g  = fminf(fmaxf(G[t], 0.0f), 1.0f);
        float wr = Wr[t], wi = Wi[t];
        wq[t] = make_float4(LN2_F * wr, LN2_F * wi, g, 0.0f);
        wb[t] = make_float2(-PI_F * g * wi, PI_F * g * wr);
    }
}

__global__ __launch_bounds__(NT, 4) void main_kernel(
    const float* __restrict__ x, const float4* __restrict__ wq,
    const float2* __restrict__ wb, float* __restrict__ out)
{
    // 32 KB. Main loop: am1 + sf planes [DIM][RPB] (16 KB).
    // Epilogue overlay: partials [4][RPB][DIM] (32 KB), A then B.
    __shared__ float sbuf[4 * RPB * DIM];
    float* am1p = sbuf;               // [DIM][RPB]
    float* sfp  = sbuf + DIM * RPB;   // [DIM][RPB]  (1.0 where x<0 else 0.0)

    const int tid   = threadIdx.x;
    const int lane  = tid & 63;
    const int w     = tid >> 6;           // 8 waves
    const int h     = w & 1;              // o-half
    const int iq    = w >> 1;             // i-quarter
    const int i0    = iq * 32;
    const int o     = h * 64 + lane;
    const int nbase = blockIdx.x * RPB;

    // Stage x tile (16 rows x 128 i = 2048 floats): float4 coalesced.
    {
        const float4* xb = (const float4*)(x + (size_t)nbase * DIM);
        float4 v = xb[tid];
        int e = tid * 4;
        int i = e & (DIM - 1), r = e >> 7;    // float4 stays in row r (0..15)
        float vv[4] = {v.x, v.y, v.z, v.w};
#pragma unroll
        for (int k = 0; k < 4; ++k) {
            am1p[(i + k) * RPB + r] = fabsf(vv[k]) - 1.0f;
            sfp[(i + k) * RPB + r]  = (vv[k] < 0.0f) ? 1.0f : 0.0f;
        }
    }
    __syncthreads();

    float accA[RPB], accB[RPB];           // scalar accumulators per row
#pragma unroll
    for (int r = 0; r < RPB; ++r) { accA[r] = 0.0f; accB[r] = 0.0f; }

    const float4* wqp = wq + (size_t)i0 * DIM + o;
    const float2* wbp = wb + (size_t)i0 * DIM + o;

    // Depth-2 weight pipeline: iter ii uses slot loaded 2 iters ago.
    float4 wq0 = wqp[0],   wq1 = wqp[DIM];
    float2 wb0 = wbp[0],   wb1 = wbp[DIM];

#pragma unroll 2
    for (int ii = 0; ii < 32; ++ii) {
        const int p2 = (ii + 2) & 31;                // wraps, in-bounds
        float4 wqn = wqp[(size_t)p2 * DIM];
        float2 wbn = wbp[(size_t)p2 * DIM];

        const int i = i0 + ii;
        // 16 rows: 4+4 broadcast ds_read_b128 (V1 ablation: loop-LDS free).
        const float4* a4 = (const float4*)(am1p + i * RPB);
        const float4* s4 = (const float4*)(sfp  + i * RPB);
        float4 aA = a4[0], aB = a4[1], aC = a4[2], aD = a4[3];
        float4 sA = s4[0], sB = s4[1], sC = s4[2], sD = s4[3];

        const float g    = wq0.z;
        const float wrl  = wq0.x, wil = wq0.y;
        const float ngwi = wb0.x, pgwr = wb0.y;      // -pi*g*wi, pi*g*wr

        const float av[16] = {aA.x, aA.y, aA.z, aA.w, aB.x, aB.y, aB.z, aB.w,
                              aC.x, aC.y, aC.z, aC.w, aD.x, aD.y, aD.z, aD.w};
        const float sv[16] = {sA.x, sA.y, sA.z, sA.w, sB.x, sB.y, sB.z, sB.w,
                              sC.x, sC.y, sC.z, sC.w, sD.x, sD.y, sD.z, sD.w};

#pragma unroll
        for (int r = 0; r < RPB; ++r) {
            float t = fmaf(g, av[r], 1.0f);          // R
            float l = __log2f(t);
            asm("" : "+v"(l));                       // block SLP re-packing
            // Same per-cell math/order as R16's packed version:
            accA[r] = fmaf(l, wrl, fmaf(sv[r], ngwi, accA[r]));
            accB[r] = fmaf(l, wil, fmaf(sv[r], pgwr, accB[r]));
        }

        wq0 = wq1; wq1 = wqn;
        wb0 = wb1; wb1 = wbn;
    }

    // Epilogue: iq-reduce via the full 32 KB buffer, A then B.
    float* pP = sbuf;                        // [4][RPB][DIM]
    const int c4 = tid * 4;                  // 4 cells per thread

    __syncthreads();   // all waves done reading planes
#pragma unroll
    for (int r = 0; r < RPB; ++r)
        pP[iq * (RPB * DIM) + r * DIM + o] = accA[r];
    __syncthreads();
    float4 A4 = make_float4(0.f, 0.f, 0.f, 0.f);
#pragma unroll
    for (int q2 = 0; q2 < 4; ++q2) {
        float4 t = *(const float4*)&pP[q2 * (RPB * DIM) + c4];
        A4.x += t.x; A4.y += t.y; A4.z += t.z; A4.w += t.w;
    }
    __syncthreads();   // before overwriting with B partials
#pragma unroll
    for (int r = 0; r < RPB; ++r)
        pP[iq * (RPB * DIM) + r * DIM + o] = accB[r];
    __syncthreads();
    float4 B4 = make_float4(0.f, 0.f, 0.f, 0.f);
#pragma unroll
    for (int q2 = 0; q2 < 4; ++q2) {
        float4 t = *(const float4*)&pP[q2 * (RPB * DIM) + c4];
        B4.x += t.x; B4.y += t.y; B4.z += t.z; B4.w += t.w;
    }

    float4 res;
    res.x = __expf(A4.x) * __cosf(B4.x);
    res.y = __expf(A4.y) * __cosf(B4.y);
    res.z = __expf(A4.z) * __cosf(B4.z);
    res.w = __expf(A4.w) * __cosf(B4.w);
    ((float4*)(out + (size_t)nbase * DIM))[tid] = res;   // coalesced dwordx4
}

// Fallback (no workspace): verified LDS-plane kernel (RPB=8 geometry),
// de-packed the same way.
__global__ __launch_bounds__(NT, 4) void fb_kernel(
    const float* __restrict__ x,
    const float* __restrict__ Wr, const float* __restrict__ Wi,
    const float* __restrict__ G, float* __restrict__ out)
{
    __shared__ float sbuf[4 * 8 * DIM];
    float* am1p = sbuf;
    float* psp  = sbuf + DIM * 8;

    const int tid   = threadIdx.x;
    const int o     = tid & (DIM - 1);
    const int q     = tid >> 7;
    const int nbase = blockIdx.x * 8;

    {
        const float* xb = x + (size_t)nbase * DIM;
        float2 v = ((const float2*)xb)[tid];
        int e = tid * 2;
        int i = e & (DIM - 1), r = e >> 7;
        am1p[i * 8 + r]       = fabsf(v.x) - 1.0f;
        am1p[(i + 1) * 8 + r] = fabsf(v.y) - 1.0f;
        psp[i * 8 + r]        = (v.x < 0.0f) ? 1.0f : 0.0f;
        psp[(i + 1) * 8 + r]  = (v.y < 0.0f) ? 1.0f : 0.0f;
    }
    __syncthreads();

    float accA[8], accB[8];
#pragma unroll
    for (int r = 0; r < 8; ++r) { accA[r] = 0.0f; accB[r] = 0.0f; }

    const int ibase = q * 32;
#pragma unroll 2
    for (int ii = 0; ii < 32; ++ii) {
        const int i = ibase + ii;
        const int wi_idx = i * DIM + o;
        float g   = fminf(fmaxf(G[wi_idx], 0.0f), 1.0f);
        float wrl = LN2_F * Wr[wi_idx];
        float wil = LN2_F * Wi[wi_idx];
        const float ngwi = -PI_F * g * (wil * (1.0f / LN2_F));
        const float pgwr =  PI_F * g * (wrl * (1.0f / LN2_F));

        const float4* a4 = (const float4*)(am1p + i * 8);
        const float4* p4 = (const float4*)(psp  + i * 8);
        float4 a03 = a4[0], a47 = a4[1];
        float4 s03 = p4[0], s47 = p4[1];
        const float av[8] = {a03.x, a03.y, a03.z, a03.w, a47.x, a47.y, a47.z, a47.w};
        const float sv[8] = {s03.x, s03.y, s03.z, s03.w, s47.x, s47.y, s47.z, s47.w};

#pragma unroll
        for (int r = 0; r < 8; ++r) {
            float t = fmaf(g, av[r], 1.0f);
            float l = __log2f(t);
            asm("" : "+v"(l));
            accA[r] = fmaf(l, wrl, fmaf(sv[r], ngwi, accA[r]));
            accB[r] = fmaf(l, wil, fmaf(sv[r], pgwr, accB[r]));
        }
    }

    float* pP = sbuf;
    const int c = tid * 2;
    const int r = c >> 7, oo = c & (DIM - 1);

    __syncthreads();
#pragma unroll
    for (int p = 0; p < 8; ++p)
        pP[q * (8 * DIM) + p * DIM + o] = accA[p];
    __syncthreads();
    float2 A = make_float2(0.f, 0.f);
#pragma unroll
    for (int qq = 0; qq < 4; ++qq) {
        float2 t = *(const float2*)&pP[qq * (8 * DIM) + r * DIM + oo];
        A.x += t.x; A.y += t.y;
    }
    __syncthreads();
#pragma unroll
    for (int p = 0; p < 8; ++p)
        pP[q * (8 * DIM) + p * DIM + o] = accB[p];
    __syncthreads();
    float2 B = make_float2(0.f, 0.f);
#pragma unroll
    for (int qq = 0; qq < 4; ++qq) {
        float2 t = *(const float2*)&pP[qq * (8 * DIM) + r * DIM + oo];
        B.x += t.x; B.y += t.y;
    }

    float2 res;
    res.x = __expf(A.x) * __cosf(B.x);
    res.y = __expf(A.y) * __cosf(B.y);
    *(float2*)&out[(size_t)(nbase + r) * DIM + oo] = res;
}

extern "C" void kernel_launch(void* const* d_in, const int* in_sizes, int n_in,
                              void* d_out, int out_size, void* d_ws, size_t ws_size,
                              hipStream_t stream) {
    const float* x  = (const float*)d_in[0];
    const float* Wr = (const float*)d_in[1];
    const float* Wi = (const float*)d_in[2];
    const float* G  = (const float*)d_in[3];
    float* out = (float*)d_out;

    const size_t wq_bytes = (size_t)DIM * DIM * sizeof(float4);   // 256 KB
    const size_t wb_bytes = (size_t)DIM * DIM * sizeof(float2);   // 128 KB
    if (ws_size >= wq_bytes + wb_bytes) {
        float4* wq = (float4*)d_ws;
        float2* wb = (float2*)((char*)d_ws + wq_bytes);
        prep<<<(DIM * DIM + 255) / 256, 256, 0, stream>>>(Wr, Wi, G, wq, wb);
        main_kernel<<<NROWS / RPB, NT, 0, stream>>>(x, wq, wb, out);
    } else {
        fb_kernel<<<NROWS / 8, NT, 0, stream>>>(x, Wr, Wi, G, out);
    }
}